// Round 6
// baseline (697.439 us; speedup 1.0000x reference)
//
#include <hip/hip_runtime.h>
#include <cstdint>
#include <cstddef>

#define DM 2048
#define DFF_ 8192
#define NR 4096        // B*S rows
#define SEQ_ 2048
#define KVB 64
#define QK_SCALE 0.2973017787506803f

typedef unsigned short u16;
typedef __attribute__((ext_vector_type(8))) __bf16 bf16x8;
typedef __attribute__((ext_vector_type(8))) unsigned short us8;
typedef __attribute__((ext_vector_type(4))) unsigned short us4;
typedef __attribute__((ext_vector_type(4))) float f32x4;

static __device__ __forceinline__ u16 f2bf(float f) {
  union { float f; unsigned u; } x; x.f = f;
  unsigned r = x.u + 0x7fffu + ((x.u >> 16) & 1u);
  return (u16)(r >> 16);
}

#define GLL(srcp, dstp) __builtin_amdgcn_global_load_lds( \
    (const __attribute__((address_space(1))) void*)(srcp), \
    (__attribute__((address_space(3))) void*)(dstp), 16, 0, 0)
#define BAR() __builtin_amdgcn_s_barrier()
#define SB0() __builtin_amdgcn_sched_barrier(0)
#define LGKM0() do { asm volatile("s_waitcnt lgkmcnt(0)" ::: "memory"); SB0(); } while (0)
#define VMCN(n)  do { asm volatile("s_waitcnt vmcnt(" #n ")" ::: "memory");  SB0(); } while (0)

// ---------------- fp32 -> bf16 conversion (vectorized, grid-stride) ----------
__global__ __launch_bounds__(256) void cvt_bf16_k(const float* __restrict__ in,
                                                  u16* __restrict__ out, int n4) {
  int i = blockIdx.x * 256 + threadIdx.x;
  int st = gridDim.x * 256;
  for (; i < n4; i += st) {
    float4 v = ((const float4*)in)[i];
    us4 o;
    o.x = f2bf(v.x); o.y = f2bf(v.y); o.z = f2bf(v.z); o.w = f2bf(v.w);
    ((us4*)out)[i] = o;
  }
}

__global__ __launch_bounds__(256) void concat3_k(const float* a, const float* b,
                                                 const float* c, float* o) {
  int i = blockIdx.x * 256 + threadIdx.x;
  if (i < DM) { o[i] = a[i]; o[DM + i] = b[i]; o[2 * DM + i] = c[i]; }
}

// ---------------- LayerNorm: fp32 in -> bf16 out, one block per row ----------
__global__ __launch_bounds__(256) void ln_k(const float* __restrict__ X,
                                            const float* __restrict__ g,
                                            const float* __restrict__ be,
                                            u16* __restrict__ out) {
  const int row = blockIdx.x, tid = threadIdx.x;
  const float* x = X + (size_t)row * DM;
  float4 a0 = ((const float4*)x)[tid];
  float4 a1 = ((const float4*)x)[tid + 256];
  float s = a0.x + a0.y + a0.z + a0.w + a1.x + a1.y + a1.z + a1.w;
  float q = a0.x*a0.x + a0.y*a0.y + a0.z*a0.z + a0.w*a0.w
          + a1.x*a1.x + a1.y*a1.y + a1.z*a1.z + a1.w*a1.w;
  #pragma unroll
  for (int off = 32; off; off >>= 1) { s += __shfl_xor(s, off); q += __shfl_xor(q, off); }
  __shared__ float red[8];
  const int w = tid >> 6, lane = tid & 63;
  if (lane == 0) { red[w] = s; red[4 + w] = q; }
  __syncthreads();
  s = red[0] + red[1] + red[2] + red[3];
  q = red[4] + red[5] + red[6] + red[7];
  const float mean = s * (1.0f / DM);
  const float rstd = rsqrtf(q * (1.0f / DM) - mean * mean + 1e-5f);
  float4 g0 = ((const float4*)g)[tid], g1 = ((const float4*)g)[tid + 256];
  float4 b0 = ((const float4*)be)[tid], b1 = ((const float4*)be)[tid + 256];
  us4 o0, o1;
  o0.x = f2bf((a0.x - mean) * rstd * g0.x + b0.x);
  o0.y = f2bf((a0.y - mean) * rstd * g0.y + b0.y);
  o0.z = f2bf((a0.z - mean) * rstd * g0.z + b0.z);
  o0.w = f2bf((a0.w - mean) * rstd * g0.w + b0.w);
  o1.x = f2bf((a1.x - mean) * rstd * g1.x + b1.x);
  o1.y = f2bf((a1.y - mean) * rstd * g1.y + b1.y);
  o1.z = f2bf((a1.z - mean) * rstd * g1.z + b1.z);
  o1.w = f2bf((a1.w - mean) * rstd * g1.w + b1.w);
  us4* op = (us4*)(out + (size_t)row * DM);
  op[tid] = o0;
  op[tid + 256] = o1;
}

// ---------------- GEMM (m201-style): BK=32 slices, slot ring, 2-phase -------
// CFG 0: BM=256,BN=256, 8 waves (2Mx4N, per-wave 128x64), 4 slots (128KB), 1 blk/CU
// CFG 1: BM=128,BN=256, 4 waves (2Mx2N, per-wave 64x128), 3 slots (72KB), 2 blk/CU
// Per slice: PH0 {read 4A+4B frags | stage A(t+AH) | BAR | lgkm0 | 16 MFMA | BAR}
//            PH1 {read 4 long-side frags | stage B(t+AH) | BAR | lgkm0 | 16 MFMA
//                 | counted vmcnt | BAR}
// Swizzle: LDS[row][ch] holds global chunk ch^((row>>1)&3); frag read chunk
// hi^((lo>>1)&3) — involution both sides, bank-conflict-free.
// MODE 1: bf16 gelu(acc+b)  MODE 2: f32 res+acc+b  MODE 4: QKV fused
template<int MODE, int CFG>
__global__ __launch_bounds__(CFG ? 256 : 512, CFG ? 2 : 1) void gemms(
    const u16* __restrict__ A, const u16* __restrict__ W,
    const float* __restrict__ bias, const float* __restrict__ res,
    void* __restrict__ o0, void* __restrict__ o1, void* __restrict__ o2,
    int N, int K, int NX) {
  constexpr int THR = CFG ? 256 : 512;
  constexpr int BM = CFG ? 128 : 256;
  constexpr int SLOTS = CFG ? 3 : 4;
  constexpr int AH = SLOTS - 1;
  constexpr int ASZ = BM * 32;
  constexpr int BSZ = 256 * 32;
  constexpr int TSZ = ASZ + BSZ;
  constexpr int ALD = (BM * 32) / (THR * 8);      // 2
  constexpr int BLD = (256 * 32) / (THR * 8);     // 2 or 4
  constexpr int MF = CFG ? 4 : 8;
  constexpr int NF = CFG ? 8 : 4;
  extern __shared__ __align__(16) u16 lds[];
  const int tid = threadIdx.x, lane = tid & 63, w = tid >> 6;
  const int hi = lane >> 4, lo = lane & 15;
  const int bid = blockIdx.x;
  const int swz = (bid & 7) * ((int)gridDim.x >> 3) + (bid >> 3);
  const size_t brow = (size_t)(swz / NX) * BM;
  const size_t bcol = (size_t)(swz % NX) * 256;
  const int wr = CFG ? ((w >> 1) * 64) : ((w >> 2) * 128);
  const int wc = CFG ? ((w & 1) * 128) : ((w & 3) * 64);
  const int kch = (hi ^ ((lo >> 1) & 3)) * 8;     // swizzled frag chunk (elems)
  // staging: per-thread sources (pre-swizzled) and linear LDS dsts
  const u16* aS[ALD]; int aD[ALD];
  #pragma unroll
  for (int g = 0; g < ALD; ++g) {
    const int idx = g * THR + tid;
    const int row = idx >> 2, ch = idx & 3;
    aS[g] = A + (brow + row) * (size_t)K + (size_t)((ch ^ ((row >> 1) & 3)) * 8);
    aD[g] = idx * 8;
  }
  const u16* bS[BLD]; int bD[BLD];
  #pragma unroll
  for (int g = 0; g < BLD; ++g) {
    const int idx = g * THR + tid;
    const int row = idx >> 2, ch = idx & 3;
    bS[g] = W + (bcol + row) * (size_t)K + (size_t)((ch ^ ((row >> 1) & 3)) * 8);
    bD[g] = idx * 8;
  }
  f32x4 acc[MF][NF] = {};
  const int NT = K >> 5;
  // prologue: stage slices 0..AH-1
  #pragma unroll
  for (int s = 0; s < AH; ++s) {
    u16* d = lds + s * TSZ;
    #pragma unroll
    for (int g = 0; g < ALD; ++g) GLL(aS[g] + s * 32, d + aD[g]);
    #pragma unroll
    for (int g = 0; g < BLD; ++g) GLL(bS[g] + s * 32, d + ASZ + bD[g]);
  }
  if constexpr (CFG) { VMCN(6); } else { VMCN(8); }
  BAR();
  int slot = 0;
  for (int t = 0; t < NT; ++t) {
    const u16* Ab = lds + slot * TSZ;
    const u16* Bb = Ab + ASZ;
    const int kb = (t + AH) * 32;
    const bool st = (t + AH) < NT;
    int s2 = slot + AH; if (s2 >= SLOTS) s2 -= SLOTS;
    u16* d2 = lds + s2 * TSZ;
    bf16x8 af[4], bf[4], xf[4];
    // ---- PH0: frags (4A + 4B) + stage A-op of slice t+AH
    if (st) {
      #pragma unroll
      for (int g = 0; g < ALD; ++g) GLL(aS[g] + kb, d2 + aD[g]);
    }
    #pragma unroll
    for (int m = 0; m < 4; ++m)
      af[m] = *(const bf16x8*)(Ab + (wr + m * 16 + lo) * 32 + kch);
    #pragma unroll
    for (int n = 0; n < 4; ++n)
      bf[n] = *(const bf16x8*)(Bb + (wc + n * 16 + lo) * 32 + kch);
    BAR(); LGKM0();
    __builtin_amdgcn_s_setprio(1);
    #pragma unroll
    for (int m = 0; m < 4; ++m)
      #pragma unroll
      for (int n = 0; n < 4; ++n)
        acc[m][n] = __builtin_amdgcn_mfma_f32_16x16x32_bf16(af[m], bf[n], acc[m][n], 0, 0, 0);
    __builtin_amdgcn_s_setprio(0);
    BAR();
    // ---- PH1: long-side second-half frags + stage B-op of slice t+AH
    if (st) {
      #pragma unroll
      for (int g = 0; g < BLD; ++g) GLL(bS[g] + kb, d2 + ASZ + bD[g]);
    }
    if constexpr (!CFG) {
      #pragma unroll
      for (int m = 0; m < 4; ++m)
        xf[m] = *(const bf16x8*)(Ab + (wr + (4 + m) * 16 + lo) * 32 + kch);
    } else {
      #pragma unroll
      for (int n = 0; n < 4; ++n)
        xf[n] = *(const bf16x8*)(Bb + (wc + (4 + n) * 16 + lo) * 32 + kch);
    }
    BAR(); LGKM0();
    __builtin_amdgcn_s_setprio(1);
    if constexpr (!CFG) {
      #pragma unroll
      for (int m = 0; m < 4; ++m)
        #pragma unroll
        for (int n = 0; n < 4; ++n)
          acc[4 + m][n] = __builtin_amdgcn_mfma_f32_16x16x32_bf16(xf[m], bf[n], acc[4 + m][n], 0, 0, 0);
    } else {
      #pragma unroll
      for (int m = 0; m < 4; ++m)
        #pragma unroll
        for (int n = 0; n < 4; ++n)
          acc[m][4 + n] = __builtin_amdgcn_mfma_f32_16x16x32_bf16(af[m], xf[n], acc[m][4 + n], 0, 0, 0);
    }
    __builtin_amdgcn_s_setprio(0);
    // counted vmcnt (tail-aware), then slice-end barrier
    if constexpr (!CFG) {
      if (t + 3 < NT) { VMCN(8); }
      else if (t + 2 < NT) { VMCN(4); }
      else if (t + 1 < NT) { VMCN(0); }
    } else {
      if (t + 2 < NT) { VMCN(6); }
      else if (t + 1 < NT) { VMCN(0); }
    }
    BAR();
    ++slot; if (slot == SLOTS) slot = 0;
  }
  // ---- epilogue
  #pragma unroll
  for (int m = 0; m < MF; ++m) {
    #pragma unroll
    for (int n = 0; n < NF; ++n) {
      const size_t col = bcol + wc + n * 16 + lo;
      const float bv = bias[col];
      const size_t rowb = brow + wr + m * 16 + hi * 4;
      if (MODE == 4) {
        const int which = (int)(col >> 11);
        const size_t c2 = col & 2047;
        if (which == 2) {
          us4 ov;
          #pragma unroll
          for (int r = 0; r < 4; ++r) ov[r] = f2bf(acc[m][n][r] + bv);
          *(us4*)((u16*)o2 + c2 * (size_t)NR + rowb) = ov;
        } else {
          u16* dst = (u16*)(which ? o1 : o0);
          #pragma unroll
          for (int r = 0; r < 4; ++r)
            dst[(rowb + r) * (size_t)DM + c2] = f2bf((acc[m][n][r] + bv) * QK_SCALE);
        }
      } else if (MODE == 1) {
        u16* dst = (u16*)o0;
        #pragma unroll
        for (int r = 0; r < 4; ++r) {
          float v = acc[m][n][r] + bv;
          float tt = 0.7978845608028654f * (v + 0.044715f * v * v * v);
          float e2 = __expf(2.0f * tt);
          float th = 1.0f - 2.0f / (e2 + 1.0f);
          dst[(rowb + r) * (size_t)N + col] = f2bf(0.5f * v * (1.0f + th));
        }
      } else {
        float* po = (float*)o0;
        #pragma unroll
        for (int r = 0; r < 4; ++r) {
          const size_t idx = (rowb + r) * (size_t)N + col;
          po[idx] = res[idx] + acc[m][n][r] + bv;
        }
      }
    }
  }
}

// ---------------- Flash attention (causal), bf16 ----------------------------
__global__ __launch_bounds__(256) void attn_k(const u16* __restrict__ Qp,
                                              const u16* __restrict__ Kp,
                                              const u16* __restrict__ Vtp,
                                              u16* __restrict__ Op) {
  const int wid = blockIdx.x;               // 0..1023
  const int qt = 31 - (wid >> 5);           // descending work
  const int bh = wid & 31;
  const int bb = bh >> 4, h = bh & 15;
  const int tid = threadIdx.x, lane = tid & 63, w = tid >> 6;
  const int hi = lane >> 4, lo = lane & 15;
  __shared__ __align__(16) u16 Klds[KVB * 128];       // [kv][d]  swizzled
  __shared__ __align__(16) u16 Vlds[128 * KVB];       // [d][kv]  swizzled
  __shared__ __align__(16) unsigned P32[4][16 * 32];  // per-wave packed P
  const size_t baseQ = ((size_t)bb * SEQ_) * DM + (size_t)h * 128;
  const size_t baseV = (size_t)h * 128 * NR + (size_t)bb * SEQ_;
  const int q0 = qt * 64 + w * 16;
  bf16x8 qf[4];
  #pragma unroll
  for (int kq = 0; kq < 4; ++kq)
    qf[kq] = *(const bf16x8*)(Qp + baseQ + (size_t)(q0 + lo) * DM + kq * 32 + hi * 8);
  f32x4 o[8] = {};
  float mrow[4], lrow[4];
  #pragma unroll
  for (int r = 0; r < 4; ++r) { mrow[r] = -1e30f; lrow[r] = 0.0f; }
  unsigned* pw = &P32[w][0];
  const int ntile = qt + 1;
  for (int t = 0; t < ntile; ++t) {
    const int kb = t * KVB;
    __syncthreads();
    #pragma unroll
    for (int c = 0; c < 4; ++c) {
      const int el = ((w * 4 + c) * 64 + lane) * 8;
      const int row = el >> 7, col = el & 127;
      const int scol = col ^ ((row & 7) << 3);
      GLL(Kp + baseQ + (size_t)(kb + row) * DM + scol, Klds + el);
    }
    #pragma unroll
    for (int c = 0; c < 4; ++c) {
      const int el = ((w * 4 + c) * 64 + lane) * 8;
      const int row = el >> 6, col = el & 63;
      const int scol = col ^ ((row & 7) << 3);
      GLL(Vtp + baseV + (size_t)row * NR + kb + scol, Vlds + el);
    }
    __syncthreads();
    f32x4 sc[4] = {};
    #pragma unroll
    for (int kq = 0; kq < 4; ++kq) {       // kq outer: no acc dep chains
      #pragma unroll
      for (int kt = 0; kt < 4; ++kt) {
        const int krow = kt * 16 + lo;
        const int coff = (kq * 32 + hi * 8) ^ ((krow & 7) << 3);
        bf16x8 kf = *(const bf16x8*)(Klds + krow * 128 + coff);
        sc[kt] = __builtin_amdgcn_mfma_f32_16x16x32_bf16(qf[kq], kf, sc[kt], 0, 0, 0);
      }
    }
    float mt[4];
    #pragma unroll
    for (int r = 0; r < 4; ++r) mt[r] = -1e30f;
    #pragma unroll
    for (int kt = 0; kt < 4; ++kt) {
      const int kg = kb + kt * 16 + lo;
      #pragma unroll
      for (int r = 0; r < 4; ++r) {
        const int qg = q0 + hi * 4 + r;
        float sv = sc[kt][r];
        sv = (kg <= qg) ? sv : -1e30f;
        sc[kt][r] = sv;
        mt[r] = fmaxf(mt[r], sv);
      }
    }
    #pragma unroll
    for (int r = 0; r < 4; ++r) {
      #pragma unroll
      for (int off = 1; off < 16; off <<= 1) mt[r] = fmaxf(mt[r], __shfl_xor(mt[r], off));
    }
    float scl[4], lt[4];
    #pragma unroll
    for (int r = 0; r < 4; ++r) {
      const float mn = fmaxf(mrow[r], mt[r]);
      scl[r] = __expf(mrow[r] - mn);
      mrow[r] = mn;
      lt[r] = 0.0f;
    }
    float pv_[4][4];
    #pragma unroll
    for (int kt = 0; kt < 4; ++kt)
      #pragma unroll
      for (int r = 0; r < 4; ++r) {
        const float p = __expf(sc[kt][r] - mrow[r]);
        pv_[kt][r] = p;
        lt[r] += p;
      }
    #pragma unroll
    for (int r = 0; r < 4; ++r) {
      #pragma unroll
      for (int off = 1; off < 16; off <<= 1) lt[r] += __shfl_xor(lt[r], off);
      lrow[r] = lrow[r] * scl[r] + lt[r];
    }
    #pragma unroll
    for (int nt = 0; nt < 8; ++nt)
      #pragma unroll
      for (int r = 0; r < 4; ++r) o[nt][r] *= scl[r];
    #pragma unroll
    for (int kt = 0; kt < 4; ++kt)
      #pragma unroll
      for (int r = 0; r < 4; ++r) {
        const float own = pv_[kt][r];
        const float pp = __shfl_xor(own, 1);
        const unsigned lo16 = (lane & 1) ? f2bf(pp) : f2bf(own);
        const unsigned hi16 = (lane & 1) ? f2bf(own) : f2bf(pp);
        const unsigned pk = lo16 | (hi16 << 16);
        if ((lane & 1) == (kt >> 1)) {
          const int row = hi * 4 + r;
          const int kp = kt * 8 + (lo >> 1);
          const int kps = (((kp >> 2) ^ (row & 7)) << 2) | (kp & 3);
          pw[row * 32 + kps] = pk;
        }
      }
    #pragma unroll
    for (int half = 0; half < 2; ++half) {
      const int ch = (half * 4 + hi) ^ (lo & 7);
      bf16x8 pf = *(const bf16x8*)((const u16*)(pw + lo * 32 + ch * 4));
      #pragma unroll
      for (int nt = 0; nt < 8; ++nt) {
        const int vrow = nt * 16 + lo;
        const int coff = (half * 32 + hi * 8) ^ ((vrow & 7) << 3);
        bf16x8 vf = *(const bf16x8*)(Vlds + vrow * 64 + coff);
        o[nt] = __builtin_amdgcn_mfma_f32_16x16x32_bf16(pf, vf, o[nt], 0, 0, 0);
      }
    }
  }
  float inv[4];
  #pragma unroll
  for (int r = 0; r < 4; ++r) inv[r] = 1.0f / lrow[r];
  #pragma unroll
  for (int nt = 0; nt < 8; ++nt)
    #pragma unroll
    for (int r = 0; r < 4; ++r) {
      const size_t row = q0 + hi * 4 + r;
      Op[baseQ + row * DM + nt * 16 + lo] = f2bf(o[nt][r] * inv[r]);
    }
}

// ---------------- launch ----------------------------------------------------
extern "C" void kernel_launch(void* const* d_in, const int* in_sizes, int n_in,
                              void* d_out, int out_size, void* d_ws, size_t ws_size,
                              hipStream_t stream) {
  (void)in_sizes; (void)n_in; (void)out_size; (void)ws_size;
  const float* X    = (const float*)d_in[0];
  const float* Wq   = (const float*)d_in[1];
  const float* bq   = (const float*)d_in[2];
  const float* Wk   = (const float*)d_in[3];
  const float* bk   = (const float*)d_in[4];
  const float* Wv   = (const float*)d_in[5];
  const float* bv   = (const float*)d_in[6];
  const float* Wo   = (const float*)d_in[7];
  const float* bo   = (const float*)d_in[8];
  const float* Win  = (const float*)d_in[9];
  const float* bin  = (const float*)d_in[10];
  const float* Wout = (const float*)d_in[11];
  const float* bout = (const float*)d_in[12];
  const float* ln1w = (const float*)d_in[13];
  const float* ln1b = (const float*)d_in[14];
  const float* ln2w = (const float*)d_in[15];
  const float* ln2b = (const float*)d_in[16];
  float* out = (float*)d_out;

  char* ws = (char*)d_ws;
  u16* wbuf  = (u16*)ws;                      // 33,554,432 B
  u16* lnb   = (u16*)(ws + 33554432);         // 16 MB
  u16* Qb    = (u16*)(ws + 50331648);
  u16* Kb    = (u16*)(ws + 67108864);
  u16* Vtb   = (u16*)(ws + 83886080);         // V transposed [d_model][b*s]
  u16* Ob    = (u16*)(ws + 100663296);
  float* bqkv = (float*)(ws + 117440512);     // 24 KB concat bias
  u16* H1    = Qb;                            // aliases Q/K (dead by MLP)

  const int LDS0 = 4 * (256 * 32 + 256 * 32) * 2;  // 131072 B (cfg A)
  const int LDS1 = 3 * (128 * 32 + 256 * 32) * 2;  // 73728 B  (cfg B)
  hipFuncSetAttribute((const void*)&gemms<4, 0>, hipFuncAttributeMaxDynamicSharedMemorySize, LDS0);
  hipFuncSetAttribute((const void*)&gemms<1, 0>, hipFuncAttributeMaxDynamicSharedMemorySize, LDS0);
  hipFuncSetAttribute((const void*)&gemms<2, 1>, hipFuncAttributeMaxDynamicSharedMemorySize, LDS1);

  // LN1
  ln_k<<<NR, 256, 0, stream>>>(X, ln1w, ln1b, lnb);
  // weights -> bf16 (Wq|Wk|Wv concat), bias concat
  cvt_bf16_k<<<2048, 256, 0, stream>>>(Wq, wbuf, DM * DM / 4);
  cvt_bf16_k<<<2048, 256, 0, stream>>>(Wk, wbuf + DM * DM, DM * DM / 4);
  cvt_bf16_k<<<2048, 256, 0, stream>>>(Wv, wbuf + 2 * DM * DM, DM * DM / 4);
  concat3_k<<<8, 256, 0, stream>>>(bq, bk, bv, bqkv);
  // fused QKV GEMM: M=4096 N=6144, grid 16x24=384 (cfg A)
  gemms<4, 0><<<384, 512, LDS0, stream>>>(lnb, wbuf, bqkv, nullptr,
                                          Qb, Kb, Vtb, 3 * DM, DM, 24);
  // attention
  attn_k<<<1024, 256, 0, stream>>>(Qb, Kb, Vtb, Ob);
  // X1 = X + attn_out @ Wo^T + bo -> d_out (fp32); grid 32x8=256 (cfg B)
  cvt_bf16_k<<<2048, 256, 0, stream>>>(Wo, wbuf, DM * DM / 4);
  gemms<2, 1><<<256, 256, LDS1, stream>>>(Ob, wbuf, bo, X,
                                          out, nullptr, nullptr, DM, DM, 8);
  // LN2
  ln_k<<<NR, 256, 0, stream>>>(out, ln2w, ln2b, lnb);
  // H1 = gelu(ln2 @ Win^T + bin); N=8192, grid 16x32=512 (cfg A)
  cvt_bf16_k<<<2048, 256, 0, stream>>>(Win, wbuf, DFF_ * DM / 4);
  gemms<1, 0><<<512, 512, LDS0, stream>>>(lnb, wbuf, bin, nullptr,
                                          H1, nullptr, nullptr, DFF_, DM, 32);
  // out = X1 + H1 @ Wout^T + bout; K=8192, grid 32x8=256 (cfg B)
  cvt_bf16_k<<<2048, 256, 0, stream>>>(Wout, wbuf, DM * DFF_ / 4);
  gemms<2, 1><<<256, 256, LDS1, stream>>>(H1, wbuf, bout, out,
                                          out, nullptr, nullptr, DM, DFF_, 8);
}